// Round 4
// baseline (161.107 us; speedup 1.0000x reference)
//
#include <hip/hip_runtime.h>
#include <hip/hip_bf16.h>

// Stratified max pooling: out[b,c] = max over j with labels[j]==c of values[b,j]
// values: [B, N] fp32, labels: [N] int32, out: [B, C] fp32.
//
// Round 10 "probe": hot loop restored to the exact round-7 form (nt dwordx4
// + plain ds atomicMax; round-9 filter removed — it was neutral, proving the
// DS pipe is not the limiter). Added strat_ghost AFTER all real work: same
// grid, same addressing, loads only (asm-consumed, no DS/stores). Its cost
// (total - 146.2 - ~2us gap) measures the pure load-path throughput of this
// access pattern and disambiguates where the 146us window goes:
//   +17-22us => loads ~6 TB/s, stream already load-bound (little headroom)
//   +40-55us => load path itself ~2 TB/s even bare (mechanism hunt, ~30us)
//   +100us+  => fills not in window; stream is the whole budget.

#define TPBS 256
#define SMAX 16                  // column splits per row
#define ENC_NEG_INF 0x007FFFFFu  // enc(-inf)

typedef float f4 __attribute__((ext_vector_type(4)));

__device__ __forceinline__ unsigned enc32(unsigned u) {
    // monotone float->uint: neg -> ~u, pos -> u|0x80000000  (branchless)
    return u ^ ((unsigned)(((int)u) >> 31) | 0x80000000u);
}
__device__ __forceinline__ float dec32(unsigned u) {
    unsigned b = u ^ (~(unsigned)(((int)u) >> 31) | 0x80000000u);
    return __uint_as_float(b);
}

// pack labels to u8 (valid: C <= 128 on main path)
__global__ __launch_bounds__(TPBS) void strat_lab8(
    const int* __restrict__ labels, unsigned char* __restrict__ l8, int N) {
    int i = blockIdx.x * TPBS + threadIdx.x;
    if (i < N) l8[i] = (unsigned char)labels[i];
}

// grid = S*B blocks; block = (s, b): flat span [s*SPAN, +SPAN) of row b.
__global__ __launch_bounds__(TPBS) void strat_stream(
    const float* __restrict__ values, const unsigned char* __restrict__ l8,
    unsigned* __restrict__ part, int B, int N, int C, int S, int SPAN, int CPAD) {
    extern __shared__ unsigned acc[];   // [4][CPAD] quadrant-replicated

    const int tid = threadIdx.x;
    const int blk = blockIdx.x;
    const int s   = blk % S;
    const int b   = blk / S;

    for (int i = tid; i < 4 * CPAD; i += TPBS) acc[i] = ENC_NEG_INF;
    __syncthreads();

    const int off0 = s * SPAN;
    const int len  = min(SPAN, N - off0);
    if (len > 0) {
        unsigned* qacc = acc + ((tid & 63) >> 4) * CPAD;  // lane quadrant
        const f4* vp = (const f4*)(values + (size_t)b * N + off0);
        const uchar4* lp = (const uchar4*)(l8 + off0);
        const int nv = len >> 2;

        for (int i = tid; i < nv; i += TPBS) {
            f4 v = __builtin_nontemporal_load(vp + i);    // 1KB contiguous/instr
            uchar4 L = lp[i];                             // L2/L3-hot
            atomicMax(&qacc[L.x], enc32(__float_as_uint(v.x)));
            atomicMax(&qacc[L.y], enc32(__float_as_uint(v.y)));
            atomicMax(&qacc[L.z], enc32(__float_as_uint(v.z)));
            atomicMax(&qacc[L.w], enc32(__float_as_uint(v.w)));
        }
        for (int j = (nv << 2) + tid; j < len; j += TPBS) {
            atomicMax(&qacc[l8[off0 + j]],
                      enc32(__float_as_uint(values[(size_t)b * N + off0 + j])));
        }
    }
    __syncthreads();

    // flush: max over 4 quadrants -> part[s][b][c]
    unsigned* dst = part + (size_t)s * B * C + (size_t)b * C;
    for (int c = tid; c < C; c += TPBS) {
        unsigned m = max(max(acc[c], acc[CPAD + c]),
                         max(acc[2 * CPAD + c], acc[3 * CPAD + c]));
        dst[c] = m;
    }
}

// loads-only ghost: identical addressing to strat_stream, no DS/stores.
// asm volatile keeps every loaded value live (anti-DCE, rule #17).
__global__ __launch_bounds__(TPBS) void strat_ghost(
    const float* __restrict__ values, const unsigned char* __restrict__ l8,
    int B, int N, int S, int SPAN) {
    const int tid = threadIdx.x;
    const int blk = blockIdx.x;
    const int s   = blk % S;
    const int b   = blk / S;

    const int off0 = s * SPAN;
    const int len  = min(SPAN, N - off0);
    if (len <= 0) return;

    const f4* vp = (const f4*)(values + (size_t)b * N + off0);
    const uchar4* lp = (const uchar4*)(l8 + off0);
    const int nv = len >> 2;

    for (int i = tid; i < nv; i += TPBS) {
        f4 v = __builtin_nontemporal_load(vp + i);
        uchar4 L = lp[i];
        unsigned lu = *(const unsigned*)&L;
        asm volatile("" :: "v"(v.x), "v"(v.y), "v"(v.z), "v"(v.w), "v"(lu));
    }
    for (int j = (nv << 2) + tid; j < len; j += TPBS) {
        float f = values[(size_t)b * N + off0 + j];
        unsigned c = l8[off0 + j];
        asm volatile("" :: "v"(f), "v"(c));
    }
}

// out[i] = dec(max over s of part[s*BC + i])
__global__ __launch_bounds__(TPBS) void strat_red(
    const unsigned* __restrict__ part, float* __restrict__ out, int BC, int S) {
    const int i = blockIdx.x * TPBS + threadIdx.x;
    if (i >= BC) return;
    const unsigned* p = part + i;
    unsigned m0 = ENC_NEG_INF, m1 = ENC_NEG_INF, m2 = ENC_NEG_INF, m3 = ENC_NEG_INF;
    int s = 0;
    for (; s + 4 <= S; s += 4) {
        m0 = max(m0, p[(size_t)(s + 0) * BC]);
        m1 = max(m1, p[(size_t)(s + 1) * BC]);
        m2 = max(m2, p[(size_t)(s + 2) * BC]);
        m3 = max(m3, p[(size_t)(s + 3) * BC]);
    }
    for (; s < S; ++s) m0 = max(m0, p[(size_t)s * BC]);
    out[i] = dec32(max(max(m0, m1), max(m2, m3)));
}

// ---------------- fallback (round-1 structure): odd shapes ------------------

#define TPB   256
#define ROWS  8
#define FCPAD 257

__device__ __forceinline__ unsigned encf(float f) {
    return enc32(__float_as_uint(f));
}

__global__ __launch_bounds__(TPB) void strat_init(unsigned* __restrict__ out_enc, int n) {
    int i = blockIdx.x * TPB + threadIdx.x;
    if (i < n) out_enc[i] = ENC_NEG_INF;
}

__global__ __launch_bounds__(TPB) void strat_main_atomic(
    const float* __restrict__ values, const int* __restrict__ labels,
    unsigned* __restrict__ out_enc, int B, int N, int C, int T) {
    __shared__ unsigned acc[ROWS * FCPAD];
    const int tid  = threadIdx.x;
    const int row0 = blockIdx.y * ROWS;
    const int rmax = min(ROWS, B - row0);

    for (int i = tid; i < ROWS * FCPAD; i += TPB) acc[i] = ENC_NEG_INF;
    __syncthreads();

    const int t = blockIdx.x;
#pragma unroll
    for (int e = 0; e < 4; ++e) {
        const int j = t * 1024 + tid * 4 + e;
        if (j < N) {
            const int c = labels[j];
            for (int r = 0; r < rmax; ++r)
                atomicMax(&acc[r * FCPAD + c],
                          encf(values[(size_t)(row0 + r) * N + j]));
        }
    }
    __syncthreads();
    for (int i = tid; i < rmax * C; i += TPB) {
        const int r = i / C, c = i - r * C;
        atomicMax(&out_enc[(size_t)(row0 + r) * C + c], acc[r * FCPAD + c]);
    }
}

__global__ __launch_bounds__(TPB) void strat_decode(unsigned* __restrict__ buf, int n) {
    int i = blockIdx.x * TPB + threadIdx.x;
    if (i < n) {
        float f = dec32(buf[i]);
        ((float*)buf)[i] = f;
    }
}

// ---------------------------------------------------------------------------

extern "C" void kernel_launch(void* const* d_in, const int* in_sizes, int n_in,
                              void* d_out, int out_size, void* d_ws, size_t ws_size,
                              hipStream_t stream) {
    const float* values = (const float*)d_in[0];
    const int*   labels = (const int*)d_in[1];
    const int N  = in_sizes[1];
    const int B  = in_sizes[0] / N;
    const int C  = out_size / B;
    const int BC = B * C;

    const int S    = SMAX;
    const int SPAN = (((N + S - 1) / S) + 3) & ~3;   // 4-aligned span
    const int CPAD = ((C + 31) / 32) * 32 + 1;       // 129 for C=100

    // d_ws layout: [labels8: N bytes][align 256][part: S*BC u32]
    const size_t part_off   = ((size_t)N + 255) & ~(size_t)255;
    const size_t part_bytes = (size_t)S * BC * sizeof(unsigned);
    const size_t lds        = (size_t)4 * CPAD * sizeof(unsigned);

    const bool main_ok = (C <= 128) && (part_off + part_bytes <= ws_size) &&
                         ((size_t)S * SPAN >= (size_t)N);

    if (main_ok) {
        unsigned char* l8   = (unsigned char*)d_ws;
        unsigned*      part = (unsigned*)((char*)d_ws + part_off);

        strat_lab8<<<(N + TPBS - 1) / TPBS, TPBS, 0, stream>>>(labels, l8, N);

        strat_stream<<<S * B, TPBS, lds, stream>>>(
            values, l8, part, B, N, C, S, SPAN, CPAD);

        strat_red<<<(BC + TPBS - 1) / TPBS, TPBS, 0, stream>>>(
            part, (float*)d_out, BC, S);

        // probe: pure load path, after all real work (no cache warming of
        // measured kernels; nt loads keep it allocation-free).
        strat_ghost<<<S * B, TPBS, 0, stream>>>(values, l8, B, N, S, SPAN);
    } else {
        unsigned* out_enc = (unsigned*)d_out;
        const int init_blocks = (out_size + TPB - 1) / TPB;
        strat_init<<<init_blocks, TPB, 0, stream>>>(out_enc, out_size);
        dim3 grid((N + 1023) / 1024, (B + ROWS - 1) / ROWS);
        strat_main_atomic<<<grid, TPB, 0, stream>>>(values, labels, out_enc, B, N, C,
                                                    (N + 1023) / 1024);
        strat_decode<<<init_blocks, TPB, 0, stream>>>(out_enc, out_size);
    }
}

// Round 5
// 150.289 us; speedup vs baseline: 1.0720x; 1.0720x over previous
//
#include <hip/hip_runtime.h>
#include <hip/hip_bf16.h>

// Stratified max pooling: out[b,c] = max over j with labels[j]==c of values[b,j]
// values: [B, N] fp32, labels: [N] int32, out: [B, C] fp32.
//
// Round 11 "fused-final": ghost probe (round 10) resolved the window:
// ~122us = 2 harness poison fills (400MB each, not ours) + ~24us owned.
// Pure load path runs at ~6-7 TB/s; stream ~20us vs 16.2us HBM floor;
// DS atomics proven non-limiting (round-9 filter neutral). Remaining lever
// is launch count: drop the strat_lab8 pre-pack and read int32 labels
// directly as int4 in the hot loop (same VMEM instr count: 1 dwordx4
// values + 1 dwordx4 labels per 4 elems; label L2 traffic 4x but far from
// the 34 TB/s L2 ceiling; no uchar4 unpack VALU). 3 dispatches -> 2.

#define TPBS 256
#define SMAX 16                  // column splits per row
#define ENC_NEG_INF 0x007FFFFFu  // enc(-inf)

typedef float f4 __attribute__((ext_vector_type(4)));

__device__ __forceinline__ unsigned enc32(unsigned u) {
    // monotone float->uint: neg -> ~u, pos -> u|0x80000000  (branchless)
    return u ^ ((unsigned)(((int)u) >> 31) | 0x80000000u);
}
__device__ __forceinline__ float dec32(unsigned u) {
    unsigned b = u ^ (~(unsigned)(((int)u) >> 31) | 0x80000000u);
    return __uint_as_float(b);
}

// grid = S*B blocks; block = (s, b): flat span [s*SPAN, +SPAN) of row b.
__global__ __launch_bounds__(TPBS) void strat_stream(
    const float* __restrict__ values, const int* __restrict__ labels,
    unsigned* __restrict__ part, int B, int N, int C, int S, int SPAN, int CPAD) {
    extern __shared__ unsigned acc[];   // [4][CPAD] quadrant-replicated

    const int tid = threadIdx.x;
    const int blk = blockIdx.x;
    const int s   = blk % S;
    const int b   = blk / S;

    for (int i = tid; i < 4 * CPAD; i += TPBS) acc[i] = ENC_NEG_INF;
    __syncthreads();

    const int off0 = s * SPAN;
    const int len  = min(SPAN, N - off0);
    if (len > 0) {
        unsigned* qacc = acc + ((tid & 63) >> 4) * CPAD;  // lane quadrant
        const f4* vp = (const f4*)(values + (size_t)b * N + off0);
        const int4* lp = (const int4*)(labels + off0);    // L2-hot across B
        const int nv = len >> 2;

        for (int i = tid; i < nv; i += TPBS) {
            f4 v = __builtin_nontemporal_load(vp + i);    // 1KB contiguous/instr
            int4 L = lp[i];
            atomicMax(&qacc[L.x], enc32(__float_as_uint(v.x)));
            atomicMax(&qacc[L.y], enc32(__float_as_uint(v.y)));
            atomicMax(&qacc[L.z], enc32(__float_as_uint(v.z)));
            atomicMax(&qacc[L.w], enc32(__float_as_uint(v.w)));
        }
        for (int j = (nv << 2) + tid; j < len; j += TPBS) {
            atomicMax(&qacc[labels[off0 + j]],
                      enc32(__float_as_uint(values[(size_t)b * N + off0 + j])));
        }
    }
    __syncthreads();

    // flush: max over 4 quadrants -> part[s][b][c]
    unsigned* dst = part + (size_t)s * B * C + (size_t)b * C;
    for (int c = tid; c < C; c += TPBS) {
        unsigned m = max(max(acc[c], acc[CPAD + c]),
                         max(acc[2 * CPAD + c], acc[3 * CPAD + c]));
        dst[c] = m;
    }
}

// out[i] = dec(max over s of part[s*BC + i])
__global__ __launch_bounds__(TPBS) void strat_red(
    const unsigned* __restrict__ part, float* __restrict__ out, int BC, int S) {
    const int i = blockIdx.x * TPBS + threadIdx.x;
    if (i >= BC) return;
    const unsigned* p = part + i;
    unsigned m0 = ENC_NEG_INF, m1 = ENC_NEG_INF, m2 = ENC_NEG_INF, m3 = ENC_NEG_INF;
    int s = 0;
    for (; s + 4 <= S; s += 4) {
        m0 = max(m0, p[(size_t)(s + 0) * BC]);
        m1 = max(m1, p[(size_t)(s + 1) * BC]);
        m2 = max(m2, p[(size_t)(s + 2) * BC]);
        m3 = max(m3, p[(size_t)(s + 3) * BC]);
    }
    for (; s < S; ++s) m0 = max(m0, p[(size_t)s * BC]);
    out[i] = dec32(max(max(m0, m1), max(m2, m3)));
}

// ---------------- fallback (round-1 structure): odd shapes ------------------

#define TPB   256
#define ROWS  8
#define FCPAD 257

__device__ __forceinline__ unsigned encf(float f) {
    return enc32(__float_as_uint(f));
}

__global__ __launch_bounds__(TPB) void strat_init(unsigned* __restrict__ out_enc, int n) {
    int i = blockIdx.x * TPB + threadIdx.x;
    if (i < n) out_enc[i] = ENC_NEG_INF;
}

__global__ __launch_bounds__(TPB) void strat_main_atomic(
    const float* __restrict__ values, const int* __restrict__ labels,
    unsigned* __restrict__ out_enc, int B, int N, int C, int T) {
    __shared__ unsigned acc[ROWS * FCPAD];
    const int tid  = threadIdx.x;
    const int row0 = blockIdx.y * ROWS;
    const int rmax = min(ROWS, B - row0);

    for (int i = tid; i < ROWS * FCPAD; i += TPB) acc[i] = ENC_NEG_INF;
    __syncthreads();

    const int t = blockIdx.x;
#pragma unroll
    for (int e = 0; e < 4; ++e) {
        const int j = t * 1024 + tid * 4 + e;
        if (j < N) {
            const int c = labels[j];
            for (int r = 0; r < rmax; ++r)
                atomicMax(&acc[r * FCPAD + c],
                          encf(values[(size_t)(row0 + r) * N + j]));
        }
    }
    __syncthreads();
    for (int i = tid; i < rmax * C; i += TPB) {
        const int r = i / C, c = i - r * C;
        atomicMax(&out_enc[(size_t)(row0 + r) * C + c], acc[r * FCPAD + c]);
    }
}

__global__ __launch_bounds__(TPB) void strat_decode(unsigned* __restrict__ buf, int n) {
    int i = blockIdx.x * TPB + threadIdx.x;
    if (i < n) {
        float f = dec32(buf[i]);
        ((float*)buf)[i] = f;
    }
}

// ---------------------------------------------------------------------------

extern "C" void kernel_launch(void* const* d_in, const int* in_sizes, int n_in,
                              void* d_out, int out_size, void* d_ws, size_t ws_size,
                              hipStream_t stream) {
    const float* values = (const float*)d_in[0];
    const int*   labels = (const int*)d_in[1];
    const int N  = in_sizes[1];
    const int B  = in_sizes[0] / N;
    const int C  = out_size / B;
    const int BC = B * C;

    const int S    = SMAX;
    const int SPAN = (((N + S - 1) / S) + 3) & ~3;   // 4-aligned span
    const int CPAD = ((C + 31) / 32) * 32 + 1;       // 129 for C=100

    // d_ws layout: [part: S*BC u32]
    const size_t part_bytes = (size_t)S * BC * sizeof(unsigned);
    const size_t lds        = (size_t)4 * CPAD * sizeof(unsigned);

    const bool main_ok = (C <= 128) && (part_bytes <= ws_size) &&
                         ((size_t)S * SPAN >= (size_t)N);

    if (main_ok) {
        unsigned* part = (unsigned*)d_ws;

        strat_stream<<<S * B, TPBS, lds, stream>>>(
            values, labels, part, B, N, C, S, SPAN, CPAD);

        strat_red<<<(BC + TPBS - 1) / TPBS, TPBS, 0, stream>>>(
            part, (float*)d_out, BC, S);
    } else {
        unsigned* out_enc = (unsigned*)d_out;
        const int init_blocks = (out_size + TPB - 1) / TPB;
        strat_init<<<init_blocks, TPB, 0, stream>>>(out_enc, out_size);
        dim3 grid((N + 1023) / 1024, (B + ROWS - 1) / ROWS);
        strat_main_atomic<<<grid, TPB, 0, stream>>>(values, labels, out_enc, B, N, C,
                                                    (N + 1023) / 1024);
        strat_decode<<<init_blocks, TPB, 0, stream>>>(out_enc, out_size);
    }
}

// Round 6
// 146.628 us; speedup vs baseline: 1.0987x; 1.0250x over previous
//
#include <hip/hip_runtime.h>
#include <hip/hip_bf16.h>

// Stratified max pooling: out[b,c] = max over j with labels[j]==c of values[b,j]
// values: [B, N] fp32, labels: [N] int32, out: [B, C] fp32.
//
// Round 12 "restore-best": exact round-7 structure (the 146.2us best).
// Session ledger: (1) L3-residency dead — harness poison fills (2x400MB,
// ~122us) sit inside the timed window and evict L3 every iteration;
// (2) DS-atomic pipe dead — read-test filter of 89% of atomics was neutral;
// (3) launch-fusion dead — int32 labels in the hot loop (+60% bytes/iter
// through L1/VMEM) cost more than the saved launch. Ghost probe: owned work
// ~24us vs 16.2us mandatory HBM floor for values. u8 label pre-pack keeps
// the hot loop at 20B/4elems — that byte-density is why this version wins.

#define TPBS 256
#define SMAX 16                  // column splits per row
#define ENC_NEG_INF 0x007FFFFFu  // enc(-inf)

typedef float f4 __attribute__((ext_vector_type(4)));

__device__ __forceinline__ unsigned enc32(unsigned u) {
    // monotone float->uint: neg -> ~u, pos -> u|0x80000000  (branchless)
    return u ^ ((unsigned)(((int)u) >> 31) | 0x80000000u);
}
__device__ __forceinline__ float dec32(unsigned u) {
    unsigned b = u ^ (~(unsigned)(((int)u) >> 31) | 0x80000000u);
    return __uint_as_float(b);
}

// pack labels to u8 (valid: C <= 128 on main path)
__global__ __launch_bounds__(TPBS) void strat_lab8(
    const int* __restrict__ labels, unsigned char* __restrict__ l8, int N) {
    int i = blockIdx.x * TPBS + threadIdx.x;
    if (i < N) l8[i] = (unsigned char)labels[i];
}

// grid = S*B blocks; block = (s, b): flat span [s*SPAN, +SPAN) of row b.
__global__ __launch_bounds__(TPBS) void strat_stream(
    const float* __restrict__ values, const unsigned char* __restrict__ l8,
    unsigned* __restrict__ part, int B, int N, int C, int S, int SPAN, int CPAD) {
    extern __shared__ unsigned acc[];   // [4][CPAD] quadrant-replicated

    const int tid = threadIdx.x;
    const int blk = blockIdx.x;
    const int s   = blk % S;
    const int b   = blk / S;

    for (int i = tid; i < 4 * CPAD; i += TPBS) acc[i] = ENC_NEG_INF;
    __syncthreads();

    const int off0 = s * SPAN;
    const int len  = min(SPAN, N - off0);
    if (len > 0) {
        unsigned* qacc = acc + ((tid & 63) >> 4) * CPAD;  // lane quadrant
        const f4* vp = (const f4*)(values + (size_t)b * N + off0);
        const uchar4* lp = (const uchar4*)(l8 + off0);
        const int nv = len >> 2;

        for (int i = tid; i < nv; i += TPBS) {
            f4 v = __builtin_nontemporal_load(vp + i);    // 1KB contiguous/instr
            uchar4 L = lp[i];                             // L2/L3-hot
            atomicMax(&qacc[L.x], enc32(__float_as_uint(v.x)));
            atomicMax(&qacc[L.y], enc32(__float_as_uint(v.y)));
            atomicMax(&qacc[L.z], enc32(__float_as_uint(v.z)));
            atomicMax(&qacc[L.w], enc32(__float_as_uint(v.w)));
        }
        for (int j = (nv << 2) + tid; j < len; j += TPBS) {
            atomicMax(&qacc[l8[off0 + j]],
                      enc32(__float_as_uint(values[(size_t)b * N + off0 + j])));
        }
    }
    __syncthreads();

    // flush: max over 4 quadrants -> part[s][b][c]
    unsigned* dst = part + (size_t)s * B * C + (size_t)b * C;
    for (int c = tid; c < C; c += TPBS) {
        unsigned m = max(max(acc[c], acc[CPAD + c]),
                         max(acc[2 * CPAD + c], acc[3 * CPAD + c]));
        dst[c] = m;
    }
}

// out[i] = dec(max over s of part[s*BC + i])
__global__ __launch_bounds__(TPBS) void strat_red(
    const unsigned* __restrict__ part, float* __restrict__ out, int BC, int S) {
    const int i = blockIdx.x * TPBS + threadIdx.x;
    if (i >= BC) return;
    const unsigned* p = part + i;
    unsigned m0 = ENC_NEG_INF, m1 = ENC_NEG_INF, m2 = ENC_NEG_INF, m3 = ENC_NEG_INF;
    int s = 0;
    for (; s + 4 <= S; s += 4) {
        m0 = max(m0, p[(size_t)(s + 0) * BC]);
        m1 = max(m1, p[(size_t)(s + 1) * BC]);
        m2 = max(m2, p[(size_t)(s + 2) * BC]);
        m3 = max(m3, p[(size_t)(s + 3) * BC]);
    }
    for (; s < S; ++s) m0 = max(m0, p[(size_t)s * BC]);
    out[i] = dec32(max(max(m0, m1), max(m2, m3)));
}

// ---------------- fallback (round-1 structure): odd shapes ------------------

#define TPB   256
#define ROWS  8
#define FCPAD 257

__device__ __forceinline__ unsigned encf(float f) {
    return enc32(__float_as_uint(f));
}

__global__ __launch_bounds__(TPB) void strat_init(unsigned* __restrict__ out_enc, int n) {
    int i = blockIdx.x * TPB + threadIdx.x;
    if (i < n) out_enc[i] = ENC_NEG_INF;
}

__global__ __launch_bounds__(TPB) void strat_main_atomic(
    const float* __restrict__ values, const int* __restrict__ labels,
    unsigned* __restrict__ out_enc, int B, int N, int C, int T) {
    __shared__ unsigned acc[ROWS * FCPAD];
    const int tid  = threadIdx.x;
    const int row0 = blockIdx.y * ROWS;
    const int rmax = min(ROWS, B - row0);

    for (int i = tid; i < ROWS * FCPAD; i += TPB) acc[i] = ENC_NEG_INF;
    __syncthreads();

    const int t = blockIdx.x;
#pragma unroll
    for (int e = 0; e < 4; ++e) {
        const int j = t * 1024 + tid * 4 + e;
        if (j < N) {
            const int c = labels[j];
            for (int r = 0; r < rmax; ++r)
                atomicMax(&acc[r * FCPAD + c],
                          encf(values[(size_t)(row0 + r) * N + j]));
        }
    }
    __syncthreads();
    for (int i = tid; i < rmax * C; i += TPB) {
        const int r = i / C, c = i - r * C;
        atomicMax(&out_enc[(size_t)(row0 + r) * C + c], acc[r * FCPAD + c]);
    }
}

__global__ __launch_bounds__(TPB) void strat_decode(unsigned* __restrict__ buf, int n) {
    int i = blockIdx.x * TPB + threadIdx.x;
    if (i < n) {
        float f = dec32(buf[i]);
        ((float*)buf)[i] = f;
    }
}

// ---------------------------------------------------------------------------

extern "C" void kernel_launch(void* const* d_in, const int* in_sizes, int n_in,
                              void* d_out, int out_size, void* d_ws, size_t ws_size,
                              hipStream_t stream) {
    const float* values = (const float*)d_in[0];
    const int*   labels = (const int*)d_in[1];
    const int N  = in_sizes[1];
    const int B  = in_sizes[0] / N;
    const int C  = out_size / B;
    const int BC = B * C;

    const int S    = SMAX;
    const int SPAN = (((N + S - 1) / S) + 3) & ~3;   // 4-aligned span
    const int CPAD = ((C + 31) / 32) * 32 + 1;       // 129 for C=100

    // d_ws layout: [labels8: N bytes][align 256][part: S*BC u32]
    const size_t part_off   = ((size_t)N + 255) & ~(size_t)255;
    const size_t part_bytes = (size_t)S * BC * sizeof(unsigned);
    const size_t lds        = (size_t)4 * CPAD * sizeof(unsigned);

    const bool main_ok = (C <= 128) && (part_off + part_bytes <= ws_size) &&
                         ((size_t)S * SPAN >= (size_t)N);

    if (main_ok) {
        unsigned char* l8   = (unsigned char*)d_ws;
        unsigned*      part = (unsigned*)((char*)d_ws + part_off);

        strat_lab8<<<(N + TPBS - 1) / TPBS, TPBS, 0, stream>>>(labels, l8, N);

        strat_stream<<<S * B, TPBS, lds, stream>>>(
            values, l8, part, B, N, C, S, SPAN, CPAD);

        strat_red<<<(BC + TPBS - 1) / TPBS, TPBS, 0, stream>>>(
            part, (float*)d_out, BC, S);
    } else {
        unsigned* out_enc = (unsigned*)d_out;
        const int init_blocks = (out_size + TPB - 1) / TPB;
        strat_init<<<init_blocks, TPB, 0, stream>>>(out_enc, out_size);
        dim3 grid((N + 1023) / 1024, (B + ROWS - 1) / ROWS);
        strat_main_atomic<<<grid, TPB, 0, stream>>>(values, labels, out_enc, B, N, C,
                                                    (N + 1023) / 1024);
        strat_decode<<<init_blocks, TPB, 0, stream>>>(out_enc, out_size);
    }
}